// Round 1
// baseline (81.667 us; speedup 1.0000x reference)
//
#include <hip/hip_runtime.h>
#include <hip/hip_bf16.h>

#define LL 128
#define HH 768
#define RR 4
#define TT 3
#define MM 256          // B*L
#define NSRC 3072       // R*H
#define KK 768

#define OFF_REL  0
#define OFF_MASK 131072
#define OFF_HSRC 131840
#define OFF_HTGT 918272

typedef __attribute__((ext_vector_type(8))) short short8;
typedef __attribute__((ext_vector_type(4))) float floatx4;

__device__ inline unsigned short f2bf(float f) {
  unsigned u = __float_as_uint(f);
  u += 0x7FFFu + ((u >> 16) & 1u);
  return (unsigned short)(u >> 16);
}

struct us4 { unsigned short x, y, z, w; };

// ---------------- fp32 -> bf16 conversion of hidden + all weights ----------------
__global__ __launch_bounds__(256) void cvt_kernel(
    const float4* __restrict__ hs, const float4* __restrict__ wsrc,
    const float4* __restrict__ wtgt, const float4* __restrict__ wd,
    us4* __restrict__ ab, us4* __restrict__ wb)
{
  const int n0 = 49152;               // hidden: 196608/4
  const int n1 = n0 + 589824;         // W_src: 2359296/4
  const int n2 = n1 + 589824;         // W_tgt
  const int n3 = n2 + 442368;         // dense_W: 1769472/4
  int stride = gridDim.x * blockDim.x;
  for (int i = blockIdx.x * blockDim.x + threadIdx.x; i < n3; i += stride) {
    const float4* src; us4* dst;
    if (i < n0)      { src = hs   + i;        dst = ab + i; }
    else if (i < n1) { src = wsrc + (i - n0); dst = wb + (i - n0); }
    else if (i < n2) { src = wtgt + (i - n1); dst = wb + 589824 + (i - n1); }
    else             { src = wd   + (i - n2); dst = wb + 1179648 + (i - n2); }
    float4 v = *src;
    us4 o; o.x = f2bf(v.x); o.y = f2bf(v.y); o.z = f2bf(v.z); o.w = f2bf(v.w);
    *dst = o;
  }
}

// ---------------- fused projection GEMM: [256 x 768] x [8448 x 768]^T ----------------
// cols [0,3072): h_src -> d_out; [3072,6144): h_tgt -> d_out; [6144,8448): z -> ws
__global__ __launch_bounds__(256) void gemm_kernel(
    const unsigned short* __restrict__ Ab, const unsigned short* __restrict__ Wb,
    const float* __restrict__ b_src, const float* __restrict__ b_tgt,
    const float* __restrict__ dense_b, float* __restrict__ out, float* __restrict__ z)
{
  int nb = blockIdx.x * 64;
  int mb = blockIdx.y * 64;
  int wave = threadIdx.x >> 6, lane = threadIdx.x & 63;
  int wm = (wave >> 1) * 32, wn = (wave & 1) * 32;
  int lr = lane & 15, lk = (lane >> 4) * 8;
  const unsigned short* ap = Ab + (mb + wm + lr) * KK + lk;
  const unsigned short* bp = Wb + (long)(nb + wn + lr) * KK + lk;
  floatx4 acc[2][2];
  #pragma unroll
  for (int mi = 0; mi < 2; ++mi)
    #pragma unroll
    for (int ni = 0; ni < 2; ++ni)
      acc[mi][ni] = (floatx4){0.f, 0.f, 0.f, 0.f};

  #pragma unroll 4
  for (int k0 = 0; k0 < KK; k0 += 32) {
    short8 a0 = *(const short8*)(ap + k0);
    short8 a1 = *(const short8*)(ap + k0 + 16 * KK);
    short8 b0 = *(const short8*)(bp + k0);
    short8 b1 = *(const short8*)(bp + k0 + 16 * KK);
    acc[0][0] = __builtin_amdgcn_mfma_f32_16x16x32_bf16(a0, b0, acc[0][0], 0, 0, 0);
    acc[0][1] = __builtin_amdgcn_mfma_f32_16x16x32_bf16(a0, b1, acc[0][1], 0, 0, 0);
    acc[1][0] = __builtin_amdgcn_mfma_f32_16x16x32_bf16(a1, b0, acc[1][0], 0, 0, 0);
    acc[1][1] = __builtin_amdgcn_mfma_f32_16x16x32_bf16(a1, b1, acc[1][1], 0, 0, 0);
  }

  int lrow = (lane >> 4) * 4;
  #pragma unroll
  for (int mi = 0; mi < 2; ++mi)
  #pragma unroll
  for (int ni = 0; ni < 2; ++ni) {
    int col  = nb + wn + ni * 16 + lr;
    int row0 = mb + wm + mi * 16 + lrow;
    float bias = (col < NSRC) ? b_src[col]
               : (col < 2 * NSRC) ? b_tgt[col - NSRC]
               : dense_b[col - 2 * NSRC];
    #pragma unroll
    for (int r2 = 0; r2 < 4; ++r2) {
      int row = row0 + r2;
      float v = acc[mi][ni][r2] + bias;
      if (col < NSRC)            out[OFF_HSRC + row * NSRC + col] = v;
      else if (col < 2 * NSRC)   out[OFF_HTGT + row * NSRC + (col - NSRC)] = v;
      else                       z[row * (TT * HH) + (col - 2 * NSRC)] = v;
    }
  }
}

// ---------------- token mask head: tanh(z) @ clf_W + clf_b ----------------
__global__ void mask_kernel(const float* __restrict__ z, const float* __restrict__ clf_W,
                            const float* __restrict__ clf_b, float* __restrict__ out)
{
  const float SCALE = 2.885390082f;  // 2*log2(e)
  int o = blockIdx.x; int lane = threadIdx.x;
  int b = o / (TT * LL); int rem = o - b * (TT * LL);
  int t = rem >> 7; int lt = rem & 127;
  const float* zr = z + ((long)(b * LL + lt) * TT + t) * HH;
  float acc = 0.f;
  for (int h = lane; h < HH; h += 64) {
    float x = zr[h];
    float th = 1.f - 2.f * __builtin_amdgcn_rcpf(1.f + __builtin_amdgcn_exp2f(SCALE * x));
    acc = fmaf(clf_W[h], th, acc);
  }
  #pragma unroll
  for (int d = 32; d; d >>= 1) acc += __shfl_down(acc, d);
  if (lane == 0) out[OFF_MASK + o] = acc + clf_b[0];
}

// ---------------- pairwise relation kernel ----------------
// rel[b,r,s,t] = sum_h tanh(hsrc[b,s,r,h] + htgt[b,t,r,h]) * w_out[h]
//             = Wsum - 2 * sum_h w[h] / (1 + exp2(SCALE*(hs+ht)))
#define HC 256
__global__ __launch_bounds__(256) void pair_kernel(
    const float* __restrict__ dout, const float* __restrict__ w_out, float* __restrict__ rel)
{
  __shared__ float sA[16][HC + 4];
  __shared__ float sB[16][HC + 4];
  __shared__ __align__(16) float sW[HC];
  __shared__ float sWsum;
  const float SCALE = 2.885390082f;
  int tid = threadIdx.x;
  int t0 = blockIdx.x * 16, s0 = blockIdx.y * 16;
  int br = blockIdx.z; int b = br >> 2; int r = br & 3;
  const float* hsrc = dout + OFF_HSRC;
  const float* htgt = dout + OFF_HTGT;

  if (tid < 64) {
    float wsm = 0.f;
    for (int h = tid; h < HH; h += 64) wsm += w_out[h];
    #pragma unroll
    for (int d = 32; d; d >>= 1) wsm += __shfl_down(wsm, d);
    if (tid == 0) sWsum = wsm;
  }

  int srow = tid >> 4, c4 = tid & 15;
  int s_ = srow, t_ = c4;
  const float* pa = hsrc + (long)((b * LL + s0 + srow) * RR + r) * HH;
  const float* pb = htgt + (long)((b * LL + t0 + srow) * RR + r) * HH;
  float acc = 0.f;

  for (int c = 0; c < HH; c += HC) {
    __syncthreads();
    #pragma unroll
    for (int p = 0; p < 4; ++p) {
      int cc = (c4 + p * 16) * 4;
      float4 va = *(const float4*)(pa + c + cc);
      float4 vb = *(const float4*)(pb + c + cc);
      va.x *= SCALE; va.y *= SCALE; va.z *= SCALE; va.w *= SCALE;
      vb.x *= SCALE; vb.y *= SCALE; vb.z *= SCALE; vb.w *= SCALE;
      *(float4*)&sA[srow][cc] = va;
      *(float4*)&sB[srow][cc] = vb;
    }
    sW[tid] = w_out[c + tid];
    __syncthreads();
    #pragma unroll 4
    for (int h = 0; h < HC; h += 4) {
      float4 va = *(const float4*)&sA[s_][h];
      float4 vb = *(const float4*)&sB[t_][h];
      float4 vw = *(const float4*)&sW[h];
      acc = fmaf(vw.x, __builtin_amdgcn_rcpf(1.f + __builtin_amdgcn_exp2f(va.x + vb.x)), acc);
      acc = fmaf(vw.y, __builtin_amdgcn_rcpf(1.f + __builtin_amdgcn_exp2f(va.y + vb.y)), acc);
      acc = fmaf(vw.z, __builtin_amdgcn_rcpf(1.f + __builtin_amdgcn_exp2f(va.z + vb.z)), acc);
      acc = fmaf(vw.w, __builtin_amdgcn_rcpf(1.f + __builtin_amdgcn_exp2f(va.w + vb.w)), acc);
    }
  }

  float res = sWsum - 2.f * acc;
  rel[((long)br * LL + (s0 + s_)) * LL + (t0 + t_)] = res;
}

extern "C" void kernel_launch(void* const* d_in, const int* in_sizes, int n_in,
                              void* d_out, int out_size, void* d_ws, size_t ws_size,
                              hipStream_t stream)
{
  const float* hidden  = (const float*)d_in[0];
  const float* W_src   = (const float*)d_in[1];
  const float* b_src   = (const float*)d_in[2];
  const float* W_tgt   = (const float*)d_in[3];
  const float* b_tgt   = (const float*)d_in[4];
  const float* w_out   = (const float*)d_in[5];
  const float* dense_W = (const float*)d_in[6];
  const float* dense_b = (const float*)d_in[7];
  const float* clf_W   = (const float*)d_in[8];
  const float* clf_b   = (const float*)d_in[9];
  float* out = (float*)d_out;
  char* ws = (char*)d_ws;

  unsigned short* Ab = (unsigned short*)ws;                        // 256x768 bf16
  unsigned short* Wb = (unsigned short*)(ws + 393216);             // 8448x768 bf16
  float* z = (float*)(ws + 393216 + 12976128);                     // 256x2304 f32

  hipLaunchKernelGGL(cvt_kernel, dim3(2048), dim3(256), 0, stream,
      (const float4*)hidden, (const float4*)W_src, (const float4*)W_tgt,
      (const float4*)dense_W, (us4*)Ab, (us4*)Wb);
  hipLaunchKernelGGL(gemm_kernel, dim3(132, 4), dim3(256), 0, stream,
      Ab, Wb, b_src, b_tgt, dense_b, out, z);
  hipLaunchKernelGGL(mask_kernel, dim3(768), dim3(64), 0, stream,
      z, clf_W, clf_b, out);
  hipLaunchKernelGGL(pair_kernel, dim3(8, 8, 8), dim3(256), 0, stream,
      out, w_out, out + OFF_REL);
}